// Round 1
// baseline (475.108 us; speedup 1.0000x reference)
//
#include <hip/hip_runtime.h>

// ---------------- degree histogram ----------------
__global__ __launch_bounds__(256) void degree_kernel(
    const int* __restrict__ src, const int* __restrict__ dst,
    int* __restrict__ dout_cnt, int* __restrict__ din_cnt, int e)
{
    int i = blockIdx.x * 256 + threadIdx.x;
    if (i < e) {
        atomicAdd(&dout_cnt[src[i]], 1);
        atomicAdd(&din_cnt[dst[i]], 1);
    }
}

// ---------------- norms ----------------
__global__ __launch_bounds__(256) void norm_kernel(
    const int* __restrict__ dout_cnt, const int* __restrict__ din_cnt,
    float* __restrict__ nsrc, float* __restrict__ ndst, int n)
{
    int i = blockIdx.x * 256 + threadIdx.x;
    if (i < n) {
        nsrc[i] = rsqrtf((float)max(dout_cnt[i], 1));
        ndst[i] = rsqrtf((float)max(din_cnt[i], 1));
    }
}

// ---------------- exclusive scan (3 phases), 1024 items per block ----------------
__global__ __launch_bounds__(256) void scan1_kernel(
    const int* __restrict__ cnt, int* __restrict__ partial,
    int* __restrict__ blockSums, int n)
{
    __shared__ int lds[256];
    int tid = threadIdx.x;
    int base = blockIdx.x * 1024 + tid * 4;
    int v0 = 0, v1 = 0, v2 = 0, v3 = 0;
    if (base + 3 < n) { v0 = cnt[base]; v1 = cnt[base+1]; v2 = cnt[base+2]; v3 = cnt[base+3]; }
    else {
        if (base     < n) v0 = cnt[base];
        if (base + 1 < n) v1 = cnt[base+1];
        if (base + 2 < n) v2 = cnt[base+2];
    }
    int tsum = v0 + v1 + v2 + v3;
    lds[tid] = tsum;
    __syncthreads();
    for (int off = 1; off < 256; off <<= 1) {
        int add = (tid >= off) ? lds[tid - off] : 0;
        __syncthreads();
        lds[tid] += add;
        __syncthreads();
    }
    int excl = lds[tid] - tsum;
    if (tid == 255) blockSums[blockIdx.x] = lds[255];
    if (base     < n) partial[base]     = excl;
    if (base + 1 < n) partial[base + 1] = excl + v0;
    if (base + 2 < n) partial[base + 2] = excl + v0 + v1;
    if (base + 3 < n) partial[base + 3] = excl + v0 + v1 + v2;
}

__global__ __launch_bounds__(1024) void scan2_kernel(
    const int* __restrict__ blockSums, int* __restrict__ blockOffsets, int nb)
{
    __shared__ int lds[1024];
    int tid = threadIdx.x;
    int v = (tid < nb) ? blockSums[tid] : 0;
    lds[tid] = v;
    __syncthreads();
    for (int off = 1; off < 1024; off <<= 1) {
        int add = (tid >= off) ? lds[tid - off] : 0;
        __syncthreads();
        lds[tid] += add;
        __syncthreads();
    }
    if (tid < nb) blockOffsets[tid] = lds[tid] - v;
}

__global__ __launch_bounds__(256) void scan3_kernel(
    const int* __restrict__ partial, const int* __restrict__ blockOffsets,
    int* __restrict__ off, int* __restrict__ cursor, int n, int e)
{
    int i = blockIdx.x * 256 + threadIdx.x;
    if (i < n) {
        int o = partial[i] + blockOffsets[i >> 10];
        off[i] = o;
        cursor[i] = o;
    }
    if (i == 0) off[n] = e;
}

// ---------------- CSR edge scatter (sort edges by dst) ----------------
__global__ __launch_bounds__(256) void scatter_kernel(
    const int* __restrict__ src, const int* __restrict__ dst,
    int* __restrict__ cursor, int* __restrict__ esrc, int e)
{
    int i = blockIdx.x * 256 + threadIdx.x;
    if (i < e) {
        int p = atomicAdd(&cursor[dst[i]], 1);
        esrc[p] = src[i];
    }
}

// ---------------- t = norm_src * (X @ W), W is [K][64] ----------------
template<int K>
__global__ __launch_bounds__(256) void gemm_norm_kernel(
    const float* __restrict__ X, const float* __restrict__ nsrc,
    const float* __restrict__ W, float* __restrict__ T, int n)
{
    constexpr int KP = K + 4;                 // padded LDS row stride (16B aligned, bank-spread)
    __shared__ float sW[K * 64];
    __shared__ float sX[16 * KP];
    int tid = threadIdx.x;
    int brow = blockIdx.x * 16;

    // stage W (K x 64) — contiguous float4 copy
    for (int i = tid; i < K * 16; i += 256)
        ((float4*)sW)[i] = ((const float4*)W)[i];
    // stage 16 rows of X
    for (int i = tid; i < 16 * (K / 4); i += 256) {
        int r = i / (K / 4), kk = i % (K / 4);
        int row = brow + r;
        float4 v = make_float4(0.f, 0.f, 0.f, 0.f);
        if (row < n) v = ((const float4*)(X + (size_t)row * K))[kk];
        *((float4*)(sX + r * KP + kk * 4)) = v;
    }
    __syncthreads();

    int ty = tid >> 4;     // row within tile (0..15)
    int tx = tid & 15;     // column group (4 cols each)
    float a0 = 0.f, a1 = 0.f, a2 = 0.f, a3 = 0.f;
    const float* xr = sX + ty * KP;
    #pragma unroll 4
    for (int k = 0; k < K; ++k) {
        float a = xr[k];
        float4 b = *((const float4*)(sW + k * 64 + tx * 4));
        a0 += a * b.x; a1 += a * b.y; a2 += a * b.z; a3 += a * b.w;
    }
    int row = brow + ty;
    if (row < n) {
        float s = nsrc[row];
        float4 o = make_float4(a0 * s, a1 * s, a2 * s, a3 * s);
        ((float4*)(T + (size_t)row * 64))[tx] = o;
    }
}

// ---------------- per-node gather aggregation: out = agg * ndst + b (opt relu) ----------------
template<bool RELU>
__global__ __launch_bounds__(256) void aggregate_kernel(
    const float* __restrict__ T, const int* __restrict__ off,
    const int* __restrict__ esrc, const float* __restrict__ ndst,
    const float* __restrict__ bias, float* __restrict__ out, int n)
{
    int wid = blockIdx.x * 4 + (threadIdx.x >> 6);   // one wave per node
    int lane = threadIdx.x & 63;                     // lane = feature
    if (wid >= n) return;
    int beg = off[wid], end = off[wid + 1];
    float a0 = 0.f, a1 = 0.f, a2 = 0.f, a3 = 0.f;
    int e = beg;
    for (; e + 4 <= end; e += 4) {
        int s0 = esrc[e], s1 = esrc[e + 1], s2 = esrc[e + 2], s3 = esrc[e + 3];
        a0 += T[(size_t)s0 * 64 + lane];
        a1 += T[(size_t)s1 * 64 + lane];
        a2 += T[(size_t)s2 * 64 + lane];
        a3 += T[(size_t)s3 * 64 + lane];
    }
    for (; e < end; ++e) a0 += T[(size_t)esrc[e] * 64 + lane];
    float v = (a0 + a1) + (a2 + a3);
    v = v * ndst[wid] + bias[lane];
    if (RELU) v = fmaxf(v, 0.f);
    out[(size_t)wid * 64 + lane] = v;
}

extern "C" void kernel_launch(void* const* d_in, const int* in_sizes, int n_in,
                              void* d_out, int out_size, void* d_ws, size_t ws_size,
                              hipStream_t stream)
{
    const float* x  = (const float*)d_in[0];
    const int*   src = (const int*)d_in[1];
    const int*   dst = (const int*)d_in[2];
    const float* W1 = (const float*)d_in[3];
    const float* b1 = (const float*)d_in[4];
    const float* W2 = (const float*)d_in[5];
    const float* b2 = (const float*)d_in[6];

    const int FIN = 128;
    const int N = in_sizes[0] / FIN;
    const int E = in_sizes[1];

    // workspace carve-up (256B aligned regions)
    char* ws = (char*)d_ws;
    size_t o = 0;
    auto carve = [&](size_t bytes) {
        void* p = ws + o;
        o = (o + bytes + 255) & ~((size_t)255);
        return p;
    };
    int* dout_cnt = (int*)carve((size_t)N * 4);
    int* din_cnt  = (int*)carve((size_t)N * 4);
    size_t cnt_bytes = (char*)din_cnt + (size_t)N * 4 - (char*)dout_cnt;
    int* partial      = (int*)carve((size_t)N * 4);
    int* blockSums    = (int*)carve(1024 * 4);
    int* blockOffsets = (int*)carve(1024 * 4);
    int* off    = (int*)carve((size_t)(N + 1) * 4);
    int* cursor = (int*)carve((size_t)N * 4);
    float* nsrc = (float*)carve((size_t)N * 4);
    float* ndst = (float*)carve((size_t)N * 4);
    int* esrc   = (int*)carve((size_t)E * 4);
    float* t    = (float*)carve((size_t)N * 64 * 4);

    float* h2 = (float*)d_out;
    float* h1 = (float*)d_out + (size_t)N * 64;

    int gb_e = (E + 255) / 256;
    int gb_n = (N + 255) / 256;
    int nb   = (N + 1023) / 1024;

    hipMemsetAsync(dout_cnt, 0, cnt_bytes, stream);
    degree_kernel<<<gb_e, 256, 0, stream>>>(src, dst, dout_cnt, din_cnt, E);
    norm_kernel<<<gb_n, 256, 0, stream>>>(dout_cnt, din_cnt, nsrc, ndst, N);
    scan1_kernel<<<nb, 256, 0, stream>>>(din_cnt, partial, blockSums, N);
    scan2_kernel<<<1, 1024, 0, stream>>>(blockSums, blockOffsets, nb);
    scan3_kernel<<<gb_n, 256, 0, stream>>>(partial, blockOffsets, off, cursor, N, E);
    scatter_kernel<<<gb_e, 256, 0, stream>>>(src, dst, cursor, esrc, E);

    // layer 1: t = nsrc*(x@W1); h1 = relu(agg(t)*ndst + b1)
    gemm_norm_kernel<128><<<(N + 15) / 16, 256, 0, stream>>>(x, nsrc, W1, t, N);
    aggregate_kernel<true><<<(N + 3) / 4, 256, 0, stream>>>(t, off, esrc, ndst, b1, h1, N);
    // layer 2: t = nsrc*(h1@W2); h2 = agg(t)*ndst + b2
    gemm_norm_kernel<64><<<(N + 15) / 16, 256, 0, stream>>>(h1, nsrc, W2, t, N);
    aggregate_kernel<false><<<(N + 3) / 4, 256, 0, stream>>>(t, off, esrc, ndst, b2, h2, N);
}

// Round 2
// 430.750 us; speedup vs baseline: 1.1030x; 1.1030x over previous
//
#include <hip/hip_runtime.h>

#define NBUCK 64

// ---------------- degree histogram ----------------
__global__ __launch_bounds__(256) void degree_kernel(
    const int* __restrict__ src, const int* __restrict__ dst,
    int* __restrict__ dout_cnt, int* __restrict__ din_cnt, int e)
{
    int i = blockIdx.x * 256 + threadIdx.x;
    if (i < e) {
        atomicAdd(&dout_cnt[src[i]], 1);
        atomicAdd(&din_cnt[dst[i]], 1);
    }
}

// ---------------- norms ----------------
__global__ __launch_bounds__(256) void norm_kernel(
    const int* __restrict__ dout_cnt, const int* __restrict__ din_cnt,
    float* __restrict__ nsrc, float* __restrict__ ndst, int n)
{
    int i = blockIdx.x * 256 + threadIdx.x;
    if (i < n) {
        nsrc[i] = rsqrtf((float)max(dout_cnt[i], 1));
        ndst[i] = rsqrtf((float)max(din_cnt[i], 1));
    }
}

// ---------------- exclusive scan (3 phases), 1024 items per block ----------------
__global__ __launch_bounds__(256) void scan1_kernel(
    const int* __restrict__ cnt, int* __restrict__ partial,
    int* __restrict__ blockSums, int n)
{
    __shared__ int lds[256];
    int tid = threadIdx.x;
    int base = blockIdx.x * 1024 + tid * 4;
    int v0 = 0, v1 = 0, v2 = 0, v3 = 0;
    if (base + 3 < n) { v0 = cnt[base]; v1 = cnt[base+1]; v2 = cnt[base+2]; v3 = cnt[base+3]; }
    else {
        if (base     < n) v0 = cnt[base];
        if (base + 1 < n) v1 = cnt[base+1];
        if (base + 2 < n) v2 = cnt[base+2];
    }
    int tsum = v0 + v1 + v2 + v3;
    lds[tid] = tsum;
    __syncthreads();
    for (int off = 1; off < 256; off <<= 1) {
        int add = (tid >= off) ? lds[tid - off] : 0;
        __syncthreads();
        lds[tid] += add;
        __syncthreads();
    }
    int excl = lds[tid] - tsum;
    if (tid == 255) blockSums[blockIdx.x] = lds[255];
    if (base     < n) partial[base]     = excl;
    if (base + 1 < n) partial[base + 1] = excl + v0;
    if (base + 2 < n) partial[base + 2] = excl + v0 + v1;
    if (base + 3 < n) partial[base + 3] = excl + v0 + v1 + v2;
}

__global__ __launch_bounds__(1024) void scan2_kernel(
    const int* __restrict__ blockSums, int* __restrict__ blockOffsets, int nb)
{
    __shared__ int lds[1024];
    int tid = threadIdx.x;
    int v = (tid < nb) ? blockSums[tid] : 0;
    lds[tid] = v;
    __syncthreads();
    for (int off = 1; off < 1024; off <<= 1) {
        int add = (tid >= off) ? lds[tid - off] : 0;
        __syncthreads();
        lds[tid] += add;
        __syncthreads();
    }
    if (tid < nb) blockOffsets[tid] = lds[tid] - v;
}

__global__ __launch_bounds__(256) void scan3_kernel(
    const int* __restrict__ partial, const int* __restrict__ blockOffsets,
    int* __restrict__ off, int* __restrict__ cursor, int* __restrict__ bucketCursor,
    int n, int e, int shift)
{
    int i = blockIdx.x * 256 + threadIdx.x;
    if (i < n) {
        int o = partial[i] + blockOffsets[i >> 10];
        off[i] = o;
        cursor[i] = o;
        if ((i & ((1 << shift) - 1)) == 0) bucketCursor[i >> shift] = o;
    }
    if (i == 0) off[n] = e;
}

// ---------------- pass 1: bucket partition by dst high bits ----------------
// 4096 edges per block; per-block LDS histogram + one global reservation per
// bucket -> each block writes ~512B contiguous chunks per bucket (full lines).
__global__ __launch_bounds__(256) void partition_kernel(
    const int* __restrict__ src, const int* __restrict__ dst,
    int* __restrict__ bucketCursor, int2* __restrict__ stage, int e, int shift)
{
    __shared__ int hist[NBUCK];
    __shared__ int base[NBUCK];
    int tid = threadIdx.x;
    if (tid < NBUCK) hist[tid] = 0;
    __syncthreads();
    int blockBase = blockIdx.x * 4096;
    int s[16], d[16], r[16];
    #pragma unroll
    for (int k = 0; k < 16; ++k) {
        int i = blockBase + k * 256 + tid;
        if (i < e) {
            s[k] = src[i];
            d[k] = dst[i];
            r[k] = atomicAdd(&hist[d[k] >> shift], 1);
        }
    }
    __syncthreads();
    if (tid < NBUCK) base[tid] = atomicAdd(&bucketCursor[tid], hist[tid]);
    __syncthreads();
    #pragma unroll
    for (int k = 0; k < 16; ++k) {
        int i = blockBase + k * 256 + tid;
        if (i < e) stage[base[d[k] >> shift] + r[k]] = make_int2(s[k], d[k]);
    }
}

// ---------------- pass 2: exact scatter within bucket-localized regions ----------------
__global__ __launch_bounds__(256) void scatter2_kernel(
    const int2* __restrict__ stage, int* __restrict__ cursor,
    int* __restrict__ esrc, int e)
{
    int i = blockIdx.x * 256 + threadIdx.x;
    if (i < e) {
        int2 ed = stage[i];
        int p = atomicAdd(&cursor[ed.y], 1);
        esrc[p] = ed.x;
    }
}

// ---------------- t = norm_src * (X @ W), W is [K][64] ----------------
template<int K>
__global__ __launch_bounds__(256) void gemm_norm_kernel(
    const float* __restrict__ X, const float* __restrict__ nsrc,
    const float* __restrict__ W, float* __restrict__ T, int n)
{
    constexpr int KP = K + 4;
    __shared__ float sW[K * 64];
    __shared__ float sX[16 * KP];
    int tid = threadIdx.x;
    int brow = blockIdx.x * 16;

    for (int i = tid; i < K * 16; i += 256)
        ((float4*)sW)[i] = ((const float4*)W)[i];
    for (int i = tid; i < 16 * (K / 4); i += 256) {
        int r = i / (K / 4), kk = i % (K / 4);
        int row = brow + r;
        float4 v = make_float4(0.f, 0.f, 0.f, 0.f);
        if (row < n) v = ((const float4*)(X + (size_t)row * K))[kk];
        *((float4*)(sX + r * KP + kk * 4)) = v;
    }
    __syncthreads();

    int ty = tid >> 4;
    int tx = tid & 15;
    float a0 = 0.f, a1 = 0.f, a2 = 0.f, a3 = 0.f;
    const float* xr = sX + ty * KP;
    #pragma unroll 4
    for (int k = 0; k < K; ++k) {
        float a = xr[k];
        float4 b = *((const float4*)(sW + k * 64 + tx * 4));
        a0 += a * b.x; a1 += a * b.y; a2 += a * b.z; a3 += a * b.w;
    }
    int row = brow + ty;
    if (row < n) {
        float s = nsrc[row];
        float4 o = make_float4(a0 * s, a1 * s, a2 * s, a3 * s);
        ((float4*)(T + (size_t)row * 64))[tx] = o;
    }
}

// ---------------- per-node gather aggregation: out = agg * ndst + b (opt relu) ----------------
template<bool RELU>
__global__ __launch_bounds__(256) void aggregate_kernel(
    const float* __restrict__ T, const int* __restrict__ off,
    const int* __restrict__ esrc, const float* __restrict__ ndst,
    const float* __restrict__ bias, float* __restrict__ out, int n)
{
    int wid = blockIdx.x * 4 + (threadIdx.x >> 6);   // one wave per node
    int lane = threadIdx.x & 63;                     // lane = feature
    if (wid >= n) return;
    int beg = off[wid], end = off[wid + 1];
    float a0 = 0.f, a1 = 0.f, a2 = 0.f, a3 = 0.f;
    int e = beg;
    for (; e + 4 <= end; e += 4) {
        int s0 = esrc[e], s1 = esrc[e + 1], s2 = esrc[e + 2], s3 = esrc[e + 3];
        a0 += T[(size_t)s0 * 64 + lane];
        a1 += T[(size_t)s1 * 64 + lane];
        a2 += T[(size_t)s2 * 64 + lane];
        a3 += T[(size_t)s3 * 64 + lane];
    }
    for (; e < end; ++e) a0 += T[(size_t)esrc[e] * 64 + lane];
    float v = (a0 + a1) + (a2 + a3);
    v = v * ndst[wid] + bias[lane];
    if (RELU) v = fmaxf(v, 0.f);
    out[(size_t)wid * 64 + lane] = v;
}

extern "C" void kernel_launch(void* const* d_in, const int* in_sizes, int n_in,
                              void* d_out, int out_size, void* d_ws, size_t ws_size,
                              hipStream_t stream)
{
    const float* x  = (const float*)d_in[0];
    const int*   src = (const int*)d_in[1];
    const int*   dst = (const int*)d_in[2];
    const float* W1 = (const float*)d_in[3];
    const float* b1 = (const float*)d_in[4];
    const float* W2 = (const float*)d_in[5];
    const float* b2 = (const float*)d_in[6];

    const int FIN = 128;
    const int N = in_sizes[0] / FIN;
    const int E = in_sizes[1];

    // bucket shift: smallest s>=11 with ((N-1)>>s) < NBUCK
    int shift = 11;
    while (((N - 1) >> shift) >= NBUCK) ++shift;

    char* ws = (char*)d_ws;
    size_t o = 0;
    auto carve = [&](size_t bytes) {
        void* p = ws + o;
        o = (o + bytes + 255) & ~((size_t)255);
        return p;
    };
    int* dout_cnt = (int*)carve((size_t)N * 4);
    int* din_cnt  = (int*)carve((size_t)N * 4);
    size_t cnt_bytes = (char*)din_cnt + (size_t)N * 4 - (char*)dout_cnt;
    int* partial      = (int*)carve((size_t)N * 4);
    int* blockSums    = (int*)carve(1024 * 4);
    int* blockOffsets = (int*)carve(1024 * 4);
    int* off    = (int*)carve((size_t)(N + 1) * 4);
    int* cursor = (int*)carve((size_t)N * 4);
    int* bucketCursor = (int*)carve(NBUCK * 4);
    float* nsrc = (float*)carve((size_t)N * 4);
    float* ndst = (float*)carve((size_t)N * 4);
    int* esrc   = (int*)carve((size_t)E * 4);
    float* t    = (float*)carve((size_t)N * 64 * 4);
    // staging aliases t: stream order guarantees t is only written (gemm1)
    // after scatter2 has consumed stage.
    int2* stage = (int2*)t;

    float* h2 = (float*)d_out;
    float* h1 = (float*)d_out + (size_t)N * 64;

    int gb_e = (E + 255) / 256;
    int gb_n = (N + 255) / 256;
    int nb   = (N + 1023) / 1024;

    hipMemsetAsync(dout_cnt, 0, cnt_bytes, stream);
    degree_kernel<<<gb_e, 256, 0, stream>>>(src, dst, dout_cnt, din_cnt, E);
    norm_kernel<<<gb_n, 256, 0, stream>>>(dout_cnt, din_cnt, nsrc, ndst, N);
    scan1_kernel<<<nb, 256, 0, stream>>>(din_cnt, partial, blockSums, N);
    scan2_kernel<<<1, 1024, 0, stream>>>(blockSums, blockOffsets, nb);
    scan3_kernel<<<gb_n, 256, 0, stream>>>(partial, blockOffsets, off, cursor,
                                           bucketCursor, N, E, shift);
    partition_kernel<<<(E + 4095) / 4096, 256, 0, stream>>>(src, dst, bucketCursor,
                                                            stage, E, shift);
    scatter2_kernel<<<gb_e, 256, 0, stream>>>(stage, cursor, esrc, E);

    // layer 1: t = nsrc*(x@W1); h1 = relu(agg(t)*ndst + b1)
    gemm_norm_kernel<128><<<(N + 15) / 16, 256, 0, stream>>>(x, nsrc, W1, t, N);
    aggregate_kernel<true><<<(N + 3) / 4, 256, 0, stream>>>(t, off, esrc, ndst, b1, h1, N);
    // layer 2: t = nsrc*(h1@W2); h2 = agg(t)*ndst + b2
    gemm_norm_kernel<64><<<(N + 15) / 16, 256, 0, stream>>>(h1, nsrc, W2, t, N);
    aggregate_kernel<false><<<(N + 3) / 4, 256, 0, stream>>>(t, off, esrc, ndst, b2, h2, N);
}

// Round 3
// 317.579 us; speedup vs baseline: 1.4960x; 1.3564x over previous
//
#include <hip/hip_runtime.h>

#define NBCAP 256          // max buckets (static LDS arrays)
#define BSHIFT 10          // 1024 nodes per bucket
#define BSZ (1 << BSHIFT)

// ---------------- k1: per-bucket edge counts (LDS-privatized) ----------------
__global__ __launch_bounds__(256) void bucket_count_kernel(
    const int* __restrict__ src, const int* __restrict__ dst,
    int* __restrict__ bcntS, int* __restrict__ bcntD, int e)
{
    __shared__ int hS[NBCAP], hD[NBCAP];
    int tid = threadIdx.x;
    for (int i = tid; i < NBCAP; i += 256) { hS[i] = 0; hD[i] = 0; }
    __syncthreads();
    int base = blockIdx.x * 4096 + tid;
    #pragma unroll
    for (int k = 0; k < 16; ++k) {
        int i = base + k * 256;
        if (i < e) {
            atomicAdd(&hS[src[i] >> BSHIFT], 1);
            atomicAdd(&hD[dst[i] >> BSHIFT], 1);
        }
    }
    __syncthreads();
    for (int i = tid; i < NBCAP; i += 256) {
        if (hS[i]) atomicAdd(&bcntS[i], hS[i]);
        if (hD[i]) atomicAdd(&bcntD[i], hD[i]);
    }
}

// ---------------- k2: bucket base scan (single block) ----------------
__global__ __launch_bounds__(256) void bucket_scan_kernel(
    const int* __restrict__ bcntS, const int* __restrict__ bcntD,
    int* __restrict__ bbaseS, int* __restrict__ bbaseD,
    int* __restrict__ curS, int* __restrict__ curD,
    int* __restrict__ off, int nb, int n, int e)
{
    __shared__ int ldsS[256], ldsD[256];
    int tid = threadIdx.x;
    int vS = (tid < nb) ? bcntS[tid] : 0;
    int vD = (tid < nb) ? bcntD[tid] : 0;
    ldsS[tid] = vS; ldsD[tid] = vD;
    __syncthreads();
    for (int o = 1; o < 256; o <<= 1) {
        int aS = (tid >= o) ? ldsS[tid - o] : 0;
        int aD = (tid >= o) ? ldsD[tid - o] : 0;
        __syncthreads();
        ldsS[tid] += aS; ldsD[tid] += aD;
        __syncthreads();
    }
    if (tid < nb) {
        int bS = ldsS[tid] - vS, bD = ldsD[tid] - vD;
        bbaseS[tid] = bS; curS[tid] = bS;
        bbaseD[tid] = bD; curD[tid] = bD;
    }
    if (tid == 0) { bbaseS[nb] = e; bbaseD[nb] = e; off[n] = e; }
}

// ---------------- k3: partition edges by src-bucket and dst-bucket ----------------
__global__ __launch_bounds__(256) void partition_kernel(
    const int* __restrict__ src, const int* __restrict__ dst,
    int* __restrict__ curS, int* __restrict__ curD,
    int* __restrict__ srcStage, int2* __restrict__ dstStage, int e)
{
    __shared__ int hS[NBCAP], hD[NBCAP], bS[NBCAP], bD[NBCAP];
    int tid = threadIdx.x;
    for (int i = tid; i < NBCAP; i += 256) { hS[i] = 0; hD[i] = 0; }
    __syncthreads();
    int blockBase = blockIdx.x * 4096;
    int s[16], d[16]; short rS[16], rD[16];
    #pragma unroll
    for (int k = 0; k < 16; ++k) {
        int i = blockBase + k * 256 + tid;
        if (i < e) {
            s[k] = src[i]; d[k] = dst[i];
            rS[k] = (short)atomicAdd(&hS[s[k] >> BSHIFT], 1);
            rD[k] = (short)atomicAdd(&hD[d[k] >> BSHIFT], 1);
        }
    }
    __syncthreads();
    for (int i = tid; i < NBCAP; i += 256) {
        bS[i] = hS[i] ? atomicAdd(&curS[i], hS[i]) : 0;
        bD[i] = hD[i] ? atomicAdd(&curD[i], hD[i]) : 0;
    }
    __syncthreads();
    #pragma unroll
    for (int k = 0; k < 16; ++k) {
        int i = blockBase + k * 256 + tid;
        if (i < e) {
            srcStage[bS[s[k] >> BSHIFT] + (int)rS[k]] = s[k];
            dstStage[bD[d[k] >> BSHIFT] + (int)rD[k]] = make_int2(s[k], d[k]);
        }
    }
}

// ---------------- k4: per-dst-bucket: din hist + CSR offsets + ndst + esrc scatter ----------------
__global__ __launch_bounds__(256) void csr_build_kernel(
    const int2* __restrict__ dstStage, const int* __restrict__ bbaseD,
    int* __restrict__ off, float* __restrict__ ndst, int* __restrict__ esrc, int n)
{
    __shared__ int cnt[BSZ];
    __shared__ int wsum[256];
    int b = blockIdx.x, tid = threadIdx.x;
    int nodeBase = b << BSHIFT;
    int nloc = min(BSZ, n - nodeBase);
    int ebeg = bbaseD[b], eend = bbaseD[b + 1];
    for (int i = tid; i < BSZ; i += 256) cnt[i] = 0;
    __syncthreads();
    for (int e = ebeg + tid; e < eend; e += 256)
        atomicAdd(&cnt[dstStage[e].y - nodeBase], 1);
    __syncthreads();
    int c0 = cnt[tid * 4], c1 = cnt[tid * 4 + 1], c2 = cnt[tid * 4 + 2], c3 = cnt[tid * 4 + 3];
    int tsum = c0 + c1 + c2 + c3;
    wsum[tid] = tsum;
    __syncthreads();
    for (int o = 1; o < 256; o <<= 1) {
        int a = (tid >= o) ? wsum[tid - o] : 0;
        __syncthreads();
        wsum[tid] += a;
        __syncthreads();
    }
    int excl = wsum[tid] - tsum;
    int p0 = excl, p1 = excl + c0, p2 = p1 + c1, p3 = p2 + c2;
    int pj[4] = { p0, p1, p2, p3 };
    int cj[4] = { c0, c1, c2, c3 };
    #pragma unroll
    for (int j = 0; j < 4; ++j) {
        int node = tid * 4 + j;
        if (node < nloc) {
            off[nodeBase + node]  = ebeg + pj[j];
            ndst[nodeBase + node] = rsqrtf((float)max(cj[j], 1));
        }
        cnt[node] = pj[j];   // becomes LDS cursor
    }
    __syncthreads();
    for (int e = ebeg + tid; e < eend; e += 256) {
        int2 ed = dstStage[e];
        int lp = atomicAdd(&cnt[ed.y - nodeBase], 1);
        esrc[ebeg + lp] = ed.x;
    }
}

// ---------------- k5: per-src-bucket: dout hist -> nsrc ----------------
__global__ __launch_bounds__(256) void dout_norm_kernel(
    const int* __restrict__ srcStage, const int* __restrict__ bbaseS,
    float* __restrict__ nsrc, int n)
{
    __shared__ int cnt[BSZ];
    int b = blockIdx.x, tid = threadIdx.x;
    int nodeBase = b << BSHIFT;
    int nloc = min(BSZ, n - nodeBase);
    for (int i = tid; i < BSZ; i += 256) cnt[i] = 0;
    __syncthreads();
    int ebeg = bbaseS[b], eend = bbaseS[b + 1];
    for (int e = ebeg + tid; e < eend; e += 256)
        atomicAdd(&cnt[srcStage[e] - nodeBase], 1);
    __syncthreads();
    for (int i = tid; i < nloc; i += 256)
        nsrc[nodeBase + i] = rsqrtf((float)max(cnt[i], 1));
}

// ---------------- t = norm_src * (X @ W), W is [K][64] ----------------
template<int K>
__global__ __launch_bounds__(256) void gemm_norm_kernel(
    const float* __restrict__ X, const float* __restrict__ nsrc,
    const float* __restrict__ W, float* __restrict__ T, int n)
{
    constexpr int KP = K + 4;
    __shared__ float sW[K * 64];
    __shared__ float sX[16 * KP];
    int tid = threadIdx.x;
    int brow = blockIdx.x * 16;

    for (int i = tid; i < K * 16; i += 256)
        ((float4*)sW)[i] = ((const float4*)W)[i];
    for (int i = tid; i < 16 * (K / 4); i += 256) {
        int r = i / (K / 4), kk = i % (K / 4);
        int row = brow + r;
        float4 v = make_float4(0.f, 0.f, 0.f, 0.f);
        if (row < n) v = ((const float4*)(X + (size_t)row * K))[kk];
        *((float4*)(sX + r * KP + kk * 4)) = v;
    }
    __syncthreads();

    int ty = tid >> 4;
    int tx = tid & 15;
    float a0 = 0.f, a1 = 0.f, a2 = 0.f, a3 = 0.f;
    const float* xr = sX + ty * KP;
    #pragma unroll 4
    for (int k = 0; k < K; ++k) {
        float a = xr[k];
        float4 b = *((const float4*)(sW + k * 64 + tx * 4));
        a0 += a * b.x; a1 += a * b.y; a2 += a * b.z; a3 += a * b.w;
    }
    int row = brow + ty;
    if (row < n) {
        float s = nsrc[row];
        float4 o = make_float4(a0 * s, a1 * s, a2 * s, a3 * s);
        ((float4*)(T + (size_t)row * 64))[tx] = o;
    }
}

// ---------------- per-node gather aggregation: out = agg * ndst + b (opt relu) ----------------
template<bool RELU>
__global__ __launch_bounds__(256) void aggregate_kernel(
    const float* __restrict__ T, const int* __restrict__ off,
    const int* __restrict__ esrc, const float* __restrict__ ndst,
    const float* __restrict__ bias, float* __restrict__ out, int n)
{
    int wid = blockIdx.x * 4 + (threadIdx.x >> 6);   // one wave per node
    int lane = threadIdx.x & 63;                     // lane = feature
    if (wid >= n) return;
    int beg = off[wid], end = off[wid + 1];
    float a0 = 0.f, a1 = 0.f, a2 = 0.f, a3 = 0.f;
    int e = beg;
    for (; e + 4 <= end; e += 4) {
        int s0 = esrc[e], s1 = esrc[e + 1], s2 = esrc[e + 2], s3 = esrc[e + 3];
        a0 += T[(size_t)s0 * 64 + lane];
        a1 += T[(size_t)s1 * 64 + lane];
        a2 += T[(size_t)s2 * 64 + lane];
        a3 += T[(size_t)s3 * 64 + lane];
    }
    for (; e < end; ++e) a0 += T[(size_t)esrc[e] * 64 + lane];
    float v = (a0 + a1) + (a2 + a3);
    v = v * ndst[wid] + bias[lane];
    if (RELU) v = fmaxf(v, 0.f);
    out[(size_t)wid * 64 + lane] = v;
}

extern "C" void kernel_launch(void* const* d_in, const int* in_sizes, int n_in,
                              void* d_out, int out_size, void* d_ws, size_t ws_size,
                              hipStream_t stream)
{
    const float* x  = (const float*)d_in[0];
    const int*   src = (const int*)d_in[1];
    const int*   dst = (const int*)d_in[2];
    const float* W1 = (const float*)d_in[3];
    const float* b1 = (const float*)d_in[4];
    const float* W2 = (const float*)d_in[5];
    const float* b2 = (const float*)d_in[6];

    const int FIN = 128;
    const int N = in_sizes[0] / FIN;
    const int E = in_sizes[1];
    const int NB = (N + BSZ - 1) >> BSHIFT;   // 98 for N=100k (<= NBCAP)

    char* ws = (char*)d_ws;
    size_t o = 0;
    auto carve = [&](size_t bytes) {
        void* p = ws + o;
        o = (o + bytes + 255) & ~((size_t)255);
        return p;
    };
    int* bcntS  = (int*)carve(NBCAP * 4);        // adjacent: one memset covers both
    int* bcntD  = (int*)((char*)bcntS + NBCAP * 4);
    o = ((size_t)((char*)bcntD + NBCAP * 4 - ws) + 255) & ~((size_t)255);
    int* bbaseS = (int*)carve((NBCAP + 1) * 4);
    int* bbaseD = (int*)carve((NBCAP + 1) * 4);
    int* curS   = (int*)carve(NBCAP * 4);
    int* curD   = (int*)carve(NBCAP * 4);
    int* off    = (int*)carve((size_t)(N + 1) * 4);
    float* nsrc = (float*)carve((size_t)N * 4);
    float* ndst = (float*)carve((size_t)N * 4);
    int* esrc   = (int*)carve((size_t)E * 4);
    size_t tbytes = (size_t)N * 64 * 4;
    size_t stbytes = (size_t)E * 12;
    float* t    = (float*)carve(tbytes > stbytes ? tbytes : stbytes);
    // stage buffers alias t: both are fully consumed (k4/k5) before gemm1 writes t
    int2* dstStage = (int2*)t;
    int*  srcStage = (int*)((char*)t + (size_t)E * 8);

    float* h2 = (float*)d_out;
    float* h1 = (float*)d_out + (size_t)N * 64;

    int gb_e4k = (E + 4095) / 4096;

    hipMemsetAsync(bcntS, 0, 2 * NBCAP * 4, stream);
    bucket_count_kernel<<<gb_e4k, 256, 0, stream>>>(src, dst, bcntS, bcntD, E);
    bucket_scan_kernel<<<1, 256, 0, stream>>>(bcntS, bcntD, bbaseS, bbaseD,
                                              curS, curD, off, NB, N, E);
    partition_kernel<<<gb_e4k, 256, 0, stream>>>(src, dst, curS, curD,
                                                 srcStage, dstStage, E);
    csr_build_kernel<<<NB, 256, 0, stream>>>(dstStage, bbaseD, off, ndst, esrc, N);
    dout_norm_kernel<<<NB, 256, 0, stream>>>(srcStage, bbaseS, nsrc, N);

    // layer 1: t = nsrc*(x@W1); h1 = relu(agg(t)*ndst + b1)
    gemm_norm_kernel<128><<<(N + 15) / 16, 256, 0, stream>>>(x, nsrc, W1, t, N);
    aggregate_kernel<true><<<(N + 3) / 4, 256, 0, stream>>>(t, off, esrc, ndst, b1, h1, N);
    // layer 2: t = nsrc*(h1@W2); h2 = agg(t)*ndst + b2
    gemm_norm_kernel<64><<<(N + 15) / 16, 256, 0, stream>>>(h1, nsrc, W2, t, N);
    aggregate_kernel<false><<<(N + 3) / 4, 256, 0, stream>>>(t, off, esrc, ndst, b2, h2, N);
}

// Round 4
// 264.848 us; speedup vs baseline: 1.7939x; 1.1991x over previous
//
#include <hip/hip_runtime.h>
#include <hip/hip_fp16.h>

#define NBCAP 256          // max buckets (static LDS arrays)
#define BSHIFT 10          // 1024 nodes per bucket
#define BSZ (1 << BSHIFT)

// ---------------- k0: init bucket cursors to padded bases ----------------
__global__ __launch_bounds__(256) void init_cursors_kernel(
    int* __restrict__ curS, int* __restrict__ curD, int nb, int capS, int capD)
{
    int i = blockIdx.x * 256 + threadIdx.x;
    if (i < nb) { curS[i] = i * capS; curD[i] = i * capD; }
}

// ---------------- k1: partition edges by src-bucket and dst-bucket ----------------
// fixed-capacity buckets; per-block LDS histogram + one global reservation per
// bucket -> coalesced chunk writes.
__global__ __launch_bounds__(256) void partition_kernel(
    const int* __restrict__ src, const int* __restrict__ dst,
    int* __restrict__ curS, int* __restrict__ curD,
    int* __restrict__ srcStage, int2* __restrict__ dstStage, int e)
{
    __shared__ int hS[NBCAP], hD[NBCAP], bS[NBCAP], bD[NBCAP];
    int tid = threadIdx.x;
    for (int i = tid; i < NBCAP; i += 256) { hS[i] = 0; hD[i] = 0; }
    __syncthreads();
    int blockBase = blockIdx.x * 4096;
    int s[16], d[16]; short rS[16], rD[16];
    #pragma unroll
    for (int k = 0; k < 16; ++k) {
        int i = blockBase + k * 256 + tid;
        if (i < e) {
            s[k] = src[i]; d[k] = dst[i];
            rS[k] = (short)atomicAdd(&hS[s[k] >> BSHIFT], 1);
            rD[k] = (short)atomicAdd(&hD[d[k] >> BSHIFT], 1);
        }
    }
    __syncthreads();
    for (int i = tid; i < NBCAP; i += 256) {
        bS[i] = hS[i] ? atomicAdd(&curS[i], hS[i]) : 0;
        bD[i] = hD[i] ? atomicAdd(&curD[i], hD[i]) : 0;
    }
    __syncthreads();
    #pragma unroll
    for (int k = 0; k < 16; ++k) {
        int i = blockBase + k * 256 + tid;
        if (i < e) {
            srcStage[bS[s[k] >> BSHIFT] + (int)rS[k]] = s[k];
            dstStage[bD[d[k] >> BSHIFT] + (int)rD[k]] = make_int2(s[k], d[k]);
        }
    }
}

// ---------------- k2: exact dst-bucket bases from cursors (single block) ----------------
__global__ __launch_bounds__(256) void bucket_scan_kernel(
    const int* __restrict__ curD, int* __restrict__ ebase,
    int* __restrict__ off, int nb, int capD, int n, int e)
{
    __shared__ int lds[256];
    int tid = threadIdx.x;
    int v = (tid < nb) ? (curD[tid] - tid * capD) : 0;
    lds[tid] = v;
    __syncthreads();
    for (int o = 1; o < 256; o <<= 1) {
        int a = (tid >= o) ? lds[tid - o] : 0;
        __syncthreads();
        lds[tid] += a;
        __syncthreads();
    }
    if (tid < nb) ebase[tid] = lds[tid] - v;
    if (tid == 0) { ebase[nb] = e; off[n] = e; }
}

// ---------------- k3: per-dst-bucket: din hist + CSR offsets + ndst + esrc scatter ----------------
__global__ __launch_bounds__(256) void csr_build_kernel(
    const int2* __restrict__ dstStage, const int* __restrict__ curD,
    const int* __restrict__ ebase, int capD,
    int* __restrict__ off, float* __restrict__ ndst, int* __restrict__ esrc, int n)
{
    __shared__ int cnt[BSZ];
    __shared__ int wsum[256];
    int b = blockIdx.x, tid = threadIdx.x;
    int nodeBase = b << BSHIFT;
    int nloc = min(BSZ, n - nodeBase);
    int sbeg = b * capD;
    int send = curD[b];
    int ebeg = ebase[b];
    for (int i = tid; i < BSZ; i += 256) cnt[i] = 0;
    __syncthreads();
    for (int e = sbeg + tid; e < send; e += 256)
        atomicAdd(&cnt[dstStage[e].y - nodeBase], 1);
    __syncthreads();
    int c0 = cnt[tid * 4], c1 = cnt[tid * 4 + 1], c2 = cnt[tid * 4 + 2], c3 = cnt[tid * 4 + 3];
    int tsum = c0 + c1 + c2 + c3;
    wsum[tid] = tsum;
    __syncthreads();
    for (int o = 1; o < 256; o <<= 1) {
        int a = (tid >= o) ? wsum[tid - o] : 0;
        __syncthreads();
        wsum[tid] += a;
        __syncthreads();
    }
    int excl = wsum[tid] - tsum;
    int pj[4] = { excl, excl + c0, excl + c0 + c1, excl + c0 + c1 + c2 };
    int cj[4] = { c0, c1, c2, c3 };
    #pragma unroll
    for (int j = 0; j < 4; ++j) {
        int node = tid * 4 + j;
        if (node < nloc) {
            off[nodeBase + node]  = ebeg + pj[j];
            ndst[nodeBase + node] = rsqrtf((float)max(cj[j], 1));
        }
        cnt[node] = pj[j];   // becomes LDS cursor
    }
    __syncthreads();
    for (int e = sbeg + tid; e < send; e += 256) {
        int2 ed = dstStage[e];
        int lp = atomicAdd(&cnt[ed.y - nodeBase], 1);
        esrc[ebeg + lp] = ed.x;
    }
}

// ---------------- k4: per-src-bucket: dout hist -> nsrc ----------------
__global__ __launch_bounds__(256) void dout_norm_kernel(
    const int* __restrict__ srcStage, const int* __restrict__ curS, int capS,
    float* __restrict__ nsrc, int n)
{
    __shared__ int cnt[BSZ];
    int b = blockIdx.x, tid = threadIdx.x;
    int nodeBase = b << BSHIFT;
    int nloc = min(BSZ, n - nodeBase);
    for (int i = tid; i < BSZ; i += 256) cnt[i] = 0;
    __syncthreads();
    int sbeg = b * capS, send = curS[b];
    for (int e = sbeg + tid; e < send; e += 256)
        atomicAdd(&cnt[srcStage[e] - nodeBase], 1);
    __syncthreads();
    for (int i = tid; i < nloc; i += 256)
        nsrc[nodeBase + i] = rsqrtf((float)max(cnt[i], 1));
}

// ---------------- t(fp16) = norm_src * (X @ W); 32-row tile, 2r x 4c per thread ----------------
template<int K>
__global__ __launch_bounds__(256) void gemm_norm_kernel(
    const float* __restrict__ X, const float* __restrict__ nsrc,
    const float* __restrict__ W, uint2* __restrict__ T, int n)
{
    constexpr int KP = K + 4;
    __shared__ float sW[K * 64];
    __shared__ float sX[32 * KP];
    int tid = threadIdx.x;
    int brow = blockIdx.x * 32;

    for (int i = tid; i < K * 16; i += 256)
        ((float4*)sW)[i] = ((const float4*)W)[i];
    for (int i = tid; i < 32 * (K / 4); i += 256) {
        int r = i / (K / 4), kk = i % (K / 4);
        int row = brow + r;
        float4 v = make_float4(0.f, 0.f, 0.f, 0.f);
        if (row < n) v = ((const float4*)(X + (size_t)row * K))[kk];
        *((float4*)(sX + r * KP + kk * 4)) = v;
    }
    __syncthreads();

    int ty = tid >> 4;       // 0..15 -> row pair
    int tx = tid & 15;       // col group of 4
    const float* x0 = sX + (ty * 2) * KP;
    const float* x1 = sX + (ty * 2 + 1) * KP;
    float a00=0,a01=0,a02=0,a03=0, a10=0,a11=0,a12=0,a13=0;
    #pragma unroll 4
    for (int k = 0; k < K; ++k) {
        float4 b = *((const float4*)(sW + k * 64 + tx * 4));
        float xa = x0[k], xb = x1[k];
        a00 += xa * b.x; a01 += xa * b.y; a02 += xa * b.z; a03 += xa * b.w;
        a10 += xb * b.x; a11 += xb * b.y; a12 += xb * b.z; a13 += xb * b.w;
    }
    int row0 = brow + ty * 2, row1 = row0 + 1;
    if (row0 < n) {
        float s = nsrc[row0];
        __half2 h0 = __floats2half2_rn(a00 * s, a01 * s);
        __half2 h1 = __floats2half2_rn(a02 * s, a03 * s);
        uint2 u; u.x = *(unsigned*)&h0; u.y = *(unsigned*)&h1;
        T[(size_t)row0 * 16 + tx] = u;
    }
    if (row1 < n) {
        float s = nsrc[row1];
        __half2 h0 = __floats2half2_rn(a10 * s, a11 * s);
        __half2 h1 = __floats2half2_rn(a12 * s, a13 * s);
        uint2 u; u.x = *(unsigned*)&h0; u.y = *(unsigned*)&h1;
        T[(size_t)row1 * 16 + tx] = u;
    }
}

// ---------------- aggregation: out = agg(Tfp16) * ndst + b (opt relu) ----------------
// one wave per node; 2 edges per pass: lanes 0-31 = edge e, lanes 32-63 = edge e+1,
// each lane loads half2 (features 2q, 2q+1); halves combined via shfl.
template<bool RELU>
__global__ __launch_bounds__(256) void aggregate_kernel(
    const __half2* __restrict__ T2, const int* __restrict__ off,
    const int* __restrict__ esrc, const float* __restrict__ ndst,
    const float* __restrict__ bias, float* __restrict__ out, int n)
{
    int wid = blockIdx.x * 4 + (threadIdx.x >> 6);
    int lane = threadIdx.x & 63;
    int q = lane & 31, side = lane >> 5;
    if (wid >= n) return;
    int beg = off[wid], end = off[wid + 1];
    float ax0 = 0.f, ay0 = 0.f, ax1 = 0.f, ay1 = 0.f;
    int e = beg;
    for (; e + 3 < end; e += 4) {
        int s0 = esrc[e + side];
        int s1 = esrc[e + 2 + side];
        float2 f0 = __half22float2(T2[(size_t)s0 * 32 + q]);
        float2 f1 = __half22float2(T2[(size_t)s1 * 32 + q]);
        ax0 += f0.x; ay0 += f0.y;
        ax1 += f1.x; ay1 += f1.y;
    }
    if (e + 1 < end) {
        int s0 = esrc[e + side];
        float2 f0 = __half22float2(T2[(size_t)s0 * 32 + q]);
        ax0 += f0.x; ay0 += f0.y;
        e += 2;
    }
    if (e < end && side == 0) {
        float2 f0 = __half22float2(T2[(size_t)esrc[e] * 32 + q]);
        ax1 += f0.x; ay1 += f0.y;
    }
    float sx = ax0 + ax1, sy = ay0 + ay1;
    sx += __shfl(sx, q + 32, 64);
    sy += __shfl(sy, q + 32, 64);
    if (side == 0) {
        float nd = ndst[wid];
        float2 bb = ((const float2*)bias)[q];
        float vx = sx * nd + bb.x;
        float vy = sy * nd + bb.y;
        if (RELU) { vx = fmaxf(vx, 0.f); vy = fmaxf(vy, 0.f); }
        ((float2*)out)[(size_t)wid * 32 + q] = make_float2(vx, vy);
    }
}

extern "C" void kernel_launch(void* const* d_in, const int* in_sizes, int n_in,
                              void* d_out, int out_size, void* d_ws, size_t ws_size,
                              hipStream_t stream)
{
    const float* x  = (const float*)d_in[0];
    const int*   src = (const int*)d_in[1];
    const int*   dst = (const int*)d_in[2];
    const float* W1 = (const float*)d_in[3];
    const float* b1 = (const float*)d_in[4];
    const float* W2 = (const float*)d_in[5];
    const float* b2 = (const float*)d_in[6];

    const int FIN = 128;
    const int N = in_sizes[0] / FIN;
    const int E = in_sizes[1];
    const int NB = (N + BSZ - 1) >> BSHIFT;   // 98 for N=100k (<= NBCAP)

    // fixed bucket capacity: avg + 2048 (>> 16 sigma for a random graph), 256-aligned
    int cap = ((E + NB - 1) / NB + 2048 + 255) & ~255;

    char* ws = (char*)d_ws;
    size_t o = 0;
    auto carve = [&](size_t bytes) {
        void* p = ws + o;
        o = (o + bytes + 255) & ~((size_t)255);
        return p;
    };
    int* curS   = (int*)carve(NBCAP * 4);
    int* curD   = (int*)carve(NBCAP * 4);
    int* ebase  = (int*)carve((NBCAP + 1) * 4);
    int* off    = (int*)carve((size_t)(N + 1) * 4);
    float* nsrc = (float*)carve((size_t)N * 4);
    float* ndst = (float*)carve((size_t)N * 4);
    int* esrc   = (int*)carve((size_t)E * 4);
    size_t tbytes  = (size_t)N * 64 * 2;                  // fp16 t
    size_t stbytes = (size_t)NB * cap * 12;               // dstStage + srcStage
    void* tstage = carve(tbytes > stbytes ? tbytes : stbytes);
    // stage buffers alias t: both fully consumed (k3/k4) before gemm1 writes t
    __half2* t     = (__half2*)tstage;
    int2* dstStage = (int2*)tstage;
    int*  srcStage = (int*)((char*)tstage + (size_t)NB * cap * 8);

    float* h2 = (float*)d_out;
    float* h1 = (float*)d_out + (size_t)N * 64;

    int gb_e4k = (E + 4095) / 4096;

    init_cursors_kernel<<<(NB + 255) / 256, 256, 0, stream>>>(curS, curD, NB, cap, cap);
    partition_kernel<<<gb_e4k, 256, 0, stream>>>(src, dst, curS, curD,
                                                 srcStage, dstStage, E);
    bucket_scan_kernel<<<1, 256, 0, stream>>>(curD, ebase, off, NB, cap, N, E);
    csr_build_kernel<<<NB, 256, 0, stream>>>(dstStage, curD, ebase, cap,
                                             off, ndst, esrc, N);
    dout_norm_kernel<<<NB, 256, 0, stream>>>(srcStage, curS, cap, nsrc, N);

    // layer 1: t = nsrc*(x@W1); h1 = relu(agg(t)*ndst + b1)
    gemm_norm_kernel<128><<<(N + 31) / 32, 256, 0, stream>>>(x, nsrc, W1, (uint2*)t, N);
    aggregate_kernel<true><<<(N + 3) / 4, 256, 0, stream>>>(t, off, esrc, ndst, b1, h1, N);
    // layer 2: t = nsrc*(h1@W2); h2 = agg(t)*ndst + b2
    gemm_norm_kernel<64><<<(N + 31) / 32, 256, 0, stream>>>(h1, nsrc, W2, (uint2*)t, N);
    aggregate_kernel<false><<<(N + 3) / 4, 256, 0, stream>>>(t, off, esrc, ndst, b2, h2, N);
}

// Round 5
// 234.998 us; speedup vs baseline: 2.0218x; 1.1270x over previous
//
#include <hip/hip_runtime.h>
#include <hip/hip_fp16.h>

#define NBCAP 256          // max buckets (static LDS arrays)
#define BSHIFT 10          // 1024 nodes per bucket
#define BSZ (1 << BSHIFT)
#define NPW 4              // nodes per wave in aggregate

// ---------------- k0: init bucket cursors to padded bases ----------------
__global__ __launch_bounds__(256) void init_cursors_kernel(
    int* __restrict__ curS, int* __restrict__ curD, int nb, int capS, int capD)
{
    int i = blockIdx.x * 256 + threadIdx.x;
    if (i < nb) { curS[i] = i * capS; curD[i] = i * capD; }
}

// ---------------- k1: partition edges by src-bucket and dst-bucket ----------------
__global__ __launch_bounds__(256) void partition_kernel(
    const int* __restrict__ src, const int* __restrict__ dst,
    int* __restrict__ curS, int* __restrict__ curD,
    int* __restrict__ srcStage, int2* __restrict__ dstStage, int e)
{
    __shared__ int hS[NBCAP], hD[NBCAP], bS[NBCAP], bD[NBCAP];
    int tid = threadIdx.x;
    for (int i = tid; i < NBCAP; i += 256) { hS[i] = 0; hD[i] = 0; }
    __syncthreads();
    int blockBase = blockIdx.x * 4096;
    int s[16], d[16]; short rS[16], rD[16];
    #pragma unroll
    for (int k = 0; k < 16; ++k) {
        int i = blockBase + k * 256 + tid;
        if (i < e) {
            s[k] = src[i]; d[k] = dst[i];
            rS[k] = (short)atomicAdd(&hS[s[k] >> BSHIFT], 1);
            rD[k] = (short)atomicAdd(&hD[d[k] >> BSHIFT], 1);
        }
    }
    __syncthreads();
    for (int i = tid; i < NBCAP; i += 256) {
        bS[i] = hS[i] ? atomicAdd(&curS[i], hS[i]) : 0;
        bD[i] = hD[i] ? atomicAdd(&curD[i], hD[i]) : 0;
    }
    __syncthreads();
    #pragma unroll
    for (int k = 0; k < 16; ++k) {
        int i = blockBase + k * 256 + tid;
        if (i < e) {
            srcStage[bS[s[k] >> BSHIFT] + (int)rS[k]] = s[k];
            dstStage[bD[d[k] >> BSHIFT] + (int)rD[k]] = make_int2(s[k], d[k]);
        }
    }
}

// ---------------- k2: exact dst-bucket bases from cursors (single block) ----------------
__global__ __launch_bounds__(256) void bucket_scan_kernel(
    const int* __restrict__ curD, int* __restrict__ ebase,
    int* __restrict__ off, int nb, int capD, int n, int e)
{
    __shared__ int lds[256];
    int tid = threadIdx.x;
    int v = (tid < nb) ? (curD[tid] - tid * capD) : 0;
    lds[tid] = v;
    __syncthreads();
    for (int o = 1; o < 256; o <<= 1) {
        int a = (tid >= o) ? lds[tid - o] : 0;
        __syncthreads();
        lds[tid] += a;
        __syncthreads();
    }
    if (tid < nb) ebase[tid] = lds[tid] - v;
    if (tid == 0) { ebase[nb] = e; off[n] = e; }
}

// ---------------- k3: per-dst-bucket: din hist + CSR offsets + ndst + esrc scatter ----------------
__global__ __launch_bounds__(256) void csr_build_kernel(
    const int2* __restrict__ dstStage, const int* __restrict__ curD,
    const int* __restrict__ ebase, int capD,
    int* __restrict__ off, float* __restrict__ ndst, int* __restrict__ esrc, int n)
{
    __shared__ int cnt[BSZ];
    __shared__ int wsum[256];
    int b = blockIdx.x, tid = threadIdx.x;
    int nodeBase = b << BSHIFT;
    int nloc = min(BSZ, n - nodeBase);
    int sbeg = b * capD;
    int send = curD[b];
    int ebeg = ebase[b];
    for (int i = tid; i < BSZ; i += 256) cnt[i] = 0;
    __syncthreads();
    for (int e = sbeg + tid; e < send; e += 256)
        atomicAdd(&cnt[dstStage[e].y - nodeBase], 1);
    __syncthreads();
    int c0 = cnt[tid * 4], c1 = cnt[tid * 4 + 1], c2 = cnt[tid * 4 + 2], c3 = cnt[tid * 4 + 3];
    int tsum = c0 + c1 + c2 + c3;
    wsum[tid] = tsum;
    __syncthreads();
    for (int o = 1; o < 256; o <<= 1) {
        int a = (tid >= o) ? wsum[tid - o] : 0;
        __syncthreads();
        wsum[tid] += a;
        __syncthreads();
    }
    int excl = wsum[tid] - tsum;
    int pj[4] = { excl, excl + c0, excl + c0 + c1, excl + c0 + c1 + c2 };
    int cj[4] = { c0, c1, c2, c3 };
    #pragma unroll
    for (int j = 0; j < 4; ++j) {
        int node = tid * 4 + j;
        if (node < nloc) {
            off[nodeBase + node]  = ebeg + pj[j];
            ndst[nodeBase + node] = rsqrtf((float)max(cj[j], 1));
        }
        cnt[node] = pj[j];   // becomes LDS cursor
    }
    __syncthreads();
    for (int e = sbeg + tid; e < send; e += 256) {
        int2 ed = dstStage[e];
        int lp = atomicAdd(&cnt[ed.y - nodeBase], 1);
        esrc[ebeg + lp] = ed.x;
    }
}

// ---------------- k4: per-src-bucket: dout hist -> nsrc ----------------
__global__ __launch_bounds__(256) void dout_norm_kernel(
    const int* __restrict__ srcStage, const int* __restrict__ curS, int capS,
    float* __restrict__ nsrc, int n)
{
    __shared__ int cnt[BSZ];
    int b = blockIdx.x, tid = threadIdx.x;
    int nodeBase = b << BSHIFT;
    int nloc = min(BSZ, n - nodeBase);
    for (int i = tid; i < BSZ; i += 256) cnt[i] = 0;
    __syncthreads();
    int sbeg = b * capS, send = curS[b];
    for (int e = sbeg + tid; e < send; e += 256)
        atomicAdd(&cnt[srcStage[e] - nodeBase], 1);
    __syncthreads();
    for (int i = tid; i < nloc; i += 256)
        nsrc[nodeBase + i] = rsqrtf((float)max(cnt[i], 1));
}

// ---------------- t(fp16) = norm_src * (X @ W); 32-row tile, 2r x 4c per thread ----------------
template<int K>
__global__ __launch_bounds__(256) void gemm_norm_kernel(
    const float* __restrict__ X, const float* __restrict__ nsrc,
    const float* __restrict__ W, uint2* __restrict__ T, int n)
{
    constexpr int KP = K + 4;
    __shared__ float sW[K * 64];
    __shared__ float sX[32 * KP];
    int tid = threadIdx.x;
    int brow = blockIdx.x * 32;

    for (int i = tid; i < K * 16; i += 256)
        ((float4*)sW)[i] = ((const float4*)W)[i];
    for (int i = tid; i < 32 * (K / 4); i += 256) {
        int r = i / (K / 4), kk = i % (K / 4);
        int row = brow + r;
        float4 v = make_float4(0.f, 0.f, 0.f, 0.f);
        if (row < n) v = ((const float4*)(X + (size_t)row * K))[kk];
        *((float4*)(sX + r * KP + kk * 4)) = v;
    }
    __syncthreads();

    int ty = tid >> 4;       // 0..15 -> row pair
    int tx = tid & 15;       // col group of 4
    const float* x0 = sX + (ty * 2) * KP;
    const float* x1 = sX + (ty * 2 + 1) * KP;
    float a00=0,a01=0,a02=0,a03=0, a10=0,a11=0,a12=0,a13=0;
    #pragma unroll 4
    for (int k = 0; k < K; ++k) {
        float4 b = *((const float4*)(sW + k * 64 + tx * 4));
        float xa = x0[k], xb = x1[k];
        a00 += xa * b.x; a01 += xa * b.y; a02 += xa * b.z; a03 += xa * b.w;
        a10 += xb * b.x; a11 += xb * b.y; a12 += xb * b.z; a13 += xb * b.w;
    }
    int row0 = brow + ty * 2, row1 = row0 + 1;
    if (row0 < n) {
        float s = nsrc[row0];
        __half2 h0 = __floats2half2_rn(a00 * s, a01 * s);
        __half2 h1 = __floats2half2_rn(a02 * s, a03 * s);
        uint2 u; u.x = *(unsigned*)&h0; u.y = *(unsigned*)&h1;
        T[(size_t)row0 * 16 + tx] = u;
    }
    if (row1 < n) {
        float s = nsrc[row1];
        __half2 h0 = __floats2half2_rn(a10 * s, a11 * s);
        __half2 h1 = __floats2half2_rn(a12 * s, a13 * s);
        uint2 u; u.x = *(unsigned*)&h0; u.y = *(unsigned*)&h1;
        T[(size_t)row1 * 16 + tx] = u;
    }
}

// ---------------- aggregation: out = agg(Tfp16) * ndst + b (opt relu) ----------------
// one wave per NPW consecutive nodes; 8 edges per pass:
// lane = (edge-group g = lane>>3, feat-chunk f = lane&7); each lane loads one
// uint4 (8 fp16 feats) -> 8 independent 16B loads in flight per pass.
// fp32 accumulate; cross-group reduce = 3 shfl_xor steps.
template<bool RELU>
__global__ __launch_bounds__(256) void aggregate_kernel(
    const uint4* __restrict__ T4, const int* __restrict__ off,
    const int* __restrict__ esrc, const float* __restrict__ ndst,
    const float* __restrict__ bias, float* __restrict__ out, int n)
{
    int wave = (blockIdx.x * 256 + threadIdx.x) >> 6;
    int lane = threadIdx.x & 63;
    int g = lane >> 3, f = lane & 7;
    float4 bb0 = ((const float4*)bias)[f * 2];
    float4 bb1 = ((const float4*)bias)[f * 2 + 1];
    int node0 = wave * NPW;
    int nodeEnd = min(node0 + NPW, n);
    for (int node = node0; node < nodeEnd; ++node) {
        int beg = off[node], end = off[node + 1];
        float a0=0,a1=0,a2=0,a3=0,a4=0,a5=0,a6=0,a7=0;
        int e = beg;
        for (; e + 8 <= end; e += 8) {
            int s = esrc[e + g];
            uint4 v = T4[(size_t)s * 8 + f];
            float2 f0 = __half22float2(*(const __half2*)&v.x);
            float2 f1 = __half22float2(*(const __half2*)&v.y);
            float2 f2 = __half22float2(*(const __half2*)&v.z);
            float2 f3 = __half22float2(*(const __half2*)&v.w);
            a0 += f0.x; a1 += f0.y; a2 += f1.x; a3 += f1.y;
            a4 += f2.x; a5 += f2.y; a6 += f3.x; a7 += f3.y;
        }
        if (e + g < end) {
            int s = esrc[e + g];
            uint4 v = T4[(size_t)s * 8 + f];
            float2 f0 = __half22float2(*(const __half2*)&v.x);
            float2 f1 = __half22float2(*(const __half2*)&v.y);
            float2 f2 = __half22float2(*(const __half2*)&v.z);
            float2 f3 = __half22float2(*(const __half2*)&v.w);
            a0 += f0.x; a1 += f0.y; a2 += f1.x; a3 += f1.y;
            a4 += f2.x; a5 += f2.y; a6 += f3.x; a7 += f3.y;
        }
        #pragma unroll
        for (int m = 8; m <= 32; m <<= 1) {
            a0 += __shfl_xor(a0, m, 64); a1 += __shfl_xor(a1, m, 64);
            a2 += __shfl_xor(a2, m, 64); a3 += __shfl_xor(a3, m, 64);
            a4 += __shfl_xor(a4, m, 64); a5 += __shfl_xor(a5, m, 64);
            a6 += __shfl_xor(a6, m, 64); a7 += __shfl_xor(a7, m, 64);
        }
        if (g == 0) {
            float nd = ndst[node];
            float4 o0 = make_float4(a0 * nd + bb0.x, a1 * nd + bb0.y,
                                    a2 * nd + bb0.z, a3 * nd + bb0.w);
            float4 o1 = make_float4(a4 * nd + bb1.x, a5 * nd + bb1.y,
                                    a6 * nd + bb1.z, a7 * nd + bb1.w);
            if (RELU) {
                o0.x = fmaxf(o0.x, 0.f); o0.y = fmaxf(o0.y, 0.f);
                o0.z = fmaxf(o0.z, 0.f); o0.w = fmaxf(o0.w, 0.f);
                o1.x = fmaxf(o1.x, 0.f); o1.y = fmaxf(o1.y, 0.f);
                o1.z = fmaxf(o1.z, 0.f); o1.w = fmaxf(o1.w, 0.f);
            }
            ((float4*)out)[(size_t)node * 16 + f * 2]     = o0;
            ((float4*)out)[(size_t)node * 16 + f * 2 + 1] = o1;
        }
    }
}

extern "C" void kernel_launch(void* const* d_in, const int* in_sizes, int n_in,
                              void* d_out, int out_size, void* d_ws, size_t ws_size,
                              hipStream_t stream)
{
    const float* x  = (const float*)d_in[0];
    const int*   src = (const int*)d_in[1];
    const int*   dst = (const int*)d_in[2];
    const float* W1 = (const float*)d_in[3];
    const float* b1 = (const float*)d_in[4];
    const float* W2 = (const float*)d_in[5];
    const float* b2 = (const float*)d_in[6];

    const int FIN = 128;
    const int N = in_sizes[0] / FIN;
    const int E = in_sizes[1];
    const int NB = (N + BSZ - 1) >> BSHIFT;   // 98 for N=100k (<= NBCAP)

    // fixed bucket capacity: avg + 2048 (>> 16 sigma for a random graph), 256-aligned
    int cap = ((E + NB - 1) / NB + 2048 + 255) & ~255;

    char* ws = (char*)d_ws;
    size_t o = 0;
    auto carve = [&](size_t bytes) {
        void* p = ws + o;
        o = (o + bytes + 255) & ~((size_t)255);
        return p;
    };
    int* curS   = (int*)carve(NBCAP * 4);
    int* curD   = (int*)carve(NBCAP * 4);
    int* ebase  = (int*)carve((NBCAP + 1) * 4);
    int* off    = (int*)carve((size_t)(N + 1) * 4);
    float* nsrc = (float*)carve((size_t)N * 4);
    float* ndst = (float*)carve((size_t)N * 4);
    int* esrc   = (int*)carve((size_t)E * 4);
    size_t tbytes  = (size_t)N * 64 * 2;                  // fp16 t
    size_t stbytes = (size_t)NB * cap * 12;               // dstStage + srcStage
    void* tstage = carve(tbytes > stbytes ? tbytes : stbytes);
    // stage buffers alias t: both fully consumed (k3/k4) before gemm1 writes t
    __half2* t     = (__half2*)tstage;
    int2* dstStage = (int2*)tstage;
    int*  srcStage = (int*)((char*)tstage + (size_t)NB * cap * 8);

    float* h2 = (float*)d_out;
    float* h1 = (float*)d_out + (size_t)N * 64;

    int gb_e4k = (E + 4095) / 4096;
    int nwaves = (N + NPW - 1) / NPW;
    int gb_agg = (nwaves + 3) / 4;

    init_cursors_kernel<<<(NB + 255) / 256, 256, 0, stream>>>(curS, curD, NB, cap, cap);
    partition_kernel<<<gb_e4k, 256, 0, stream>>>(src, dst, curS, curD,
                                                 srcStage, dstStage, E);
    bucket_scan_kernel<<<1, 256, 0, stream>>>(curD, ebase, off, NB, cap, N, E);
    csr_build_kernel<<<NB, 256, 0, stream>>>(dstStage, curD, ebase, cap,
                                             off, ndst, esrc, N);
    dout_norm_kernel<<<NB, 256, 0, stream>>>(srcStage, curS, cap, nsrc, N);

    // layer 1: t = nsrc*(x@W1); h1 = relu(agg(t)*ndst + b1)
    gemm_norm_kernel<128><<<(N + 31) / 32, 256, 0, stream>>>(x, nsrc, W1, (uint2*)t, N);
    aggregate_kernel<true><<<gb_agg, 256, 0, stream>>>((const uint4*)t, off, esrc, ndst, b1, h1, N);
    // layer 2: t = nsrc*(h1@W2); h2 = agg(t)*ndst + b2
    gemm_norm_kernel<64><<<(N + 31) / 32, 256, 0, stream>>>(h1, nsrc, W2, (uint2*)t, N);
    aggregate_kernel<false><<<gb_agg, 256, 0, stream>>>((const uint4*)t, off, esrc, ndst, b2, h2, N);
}

// Round 6
// 202.983 us; speedup vs baseline: 2.3406x; 1.1577x over previous
//
#include <hip/hip_runtime.h>
#include <hip/hip_fp16.h>

#define NBCAP 256          // max buckets (static LDS arrays)
#define BSHIFT 10          // 1024 nodes per bucket
#define BSZ (1 << BSHIFT)
#define NPW 4              // nodes per wave in aggregate

typedef _Float16 f16x8 __attribute__((ext_vector_type(8)));
typedef float f32x4 __attribute__((ext_vector_type(4)));

// ---------------- k0: init bucket cursors to padded bases ----------------
__global__ __launch_bounds__(256) void init_cursors_kernel(
    int* __restrict__ curS, int* __restrict__ curD, int nb, int capS, int capD)
{
    int i = blockIdx.x * 256 + threadIdx.x;
    if (i < nb) { curS[i] = i * capS; curD[i] = i * capD; }
}

// ---------------- k1: partition edges by src-bucket and dst-bucket ----------------
// srcStage entry: local src id (ushort). dstStage entry: (dstLocal<<22)|src.
__global__ __launch_bounds__(256) void partition_kernel(
    const int* __restrict__ src, const int* __restrict__ dst,
    int* __restrict__ curS, int* __restrict__ curD,
    unsigned short* __restrict__ srcStage, unsigned* __restrict__ dstStage, int e)
{
    __shared__ int hS[NBCAP], hD[NBCAP], bS[NBCAP], bD[NBCAP];
    int tid = threadIdx.x;
    for (int i = tid; i < NBCAP; i += 256) { hS[i] = 0; hD[i] = 0; }
    __syncthreads();
    int blockBase = blockIdx.x * 4096;
    int s[16], d[16]; short rS[16], rD[16];
    #pragma unroll
    for (int k = 0; k < 16; ++k) {
        int i = blockBase + k * 256 + tid;
        if (i < e) {
            s[k] = src[i]; d[k] = dst[i];
            rS[k] = (short)atomicAdd(&hS[s[k] >> BSHIFT], 1);
            rD[k] = (short)atomicAdd(&hD[d[k] >> BSHIFT], 1);
        }
    }
    __syncthreads();
    for (int i = tid; i < NBCAP; i += 256) {
        bS[i] = hS[i] ? atomicAdd(&curS[i], hS[i]) : 0;
        bD[i] = hD[i] ? atomicAdd(&curD[i], hD[i]) : 0;
    }
    __syncthreads();
    #pragma unroll
    for (int k = 0; k < 16; ++k) {
        int i = blockBase + k * 256 + tid;
        if (i < e) {
            srcStage[bS[s[k] >> BSHIFT] + (int)rS[k]] = (unsigned short)(s[k] & (BSZ - 1));
            dstStage[bD[d[k] >> BSHIFT] + (int)rD[k]] =
                ((unsigned)(d[k] & (BSZ - 1)) << 22) | (unsigned)s[k];
        }
    }
}

// ---------------- k2: exact dst-bucket bases from cursors (single block) ----------------
__global__ __launch_bounds__(256) void bucket_scan_kernel(
    const int* __restrict__ curD, int* __restrict__ ebase,
    int* __restrict__ off, int nb, int capD, int n, int e)
{
    __shared__ int lds[256];
    int tid = threadIdx.x;
    int v = (tid < nb) ? (curD[tid] - tid * capD) : 0;
    lds[tid] = v;
    __syncthreads();
    for (int o = 1; o < 256; o <<= 1) {
        int a = (tid >= o) ? lds[tid - o] : 0;
        __syncthreads();
        lds[tid] += a;
        __syncthreads();
    }
    if (tid < nb) ebase[tid] = lds[tid] - v;
    if (tid == 0) { ebase[nb] = e; off[n] = e; }
}

// ---------------- k3: per-dst-bucket: din hist + CSR offsets + ndst + esrc scatter ----------------
__global__ __launch_bounds__(256) void csr_build_kernel(
    const unsigned* __restrict__ dstStage, const int* __restrict__ curD,
    const int* __restrict__ ebase, int capD,
    int* __restrict__ off, float* __restrict__ ndst, int* __restrict__ esrc, int n)
{
    __shared__ int cnt[BSZ];
    __shared__ int wsum[256];
    int b = blockIdx.x, tid = threadIdx.x;
    int nodeBase = b << BSHIFT;
    int nloc = min(BSZ, n - nodeBase);
    int sbeg = b * capD;
    int send = curD[b];
    int ebeg = ebase[b];
    for (int i = tid; i < BSZ; i += 256) cnt[i] = 0;
    __syncthreads();
    for (int e = sbeg + tid; e < send; e += 256)
        atomicAdd(&cnt[dstStage[e] >> 22], 1);
    __syncthreads();
    int c0 = cnt[tid * 4], c1 = cnt[tid * 4 + 1], c2 = cnt[tid * 4 + 2], c3 = cnt[tid * 4 + 3];
    int tsum = c0 + c1 + c2 + c3;
    wsum[tid] = tsum;
    __syncthreads();
    for (int o = 1; o < 256; o <<= 1) {
        int a = (tid >= o) ? wsum[tid - o] : 0;
        __syncthreads();
        wsum[tid] += a;
        __syncthreads();
    }
    int excl = wsum[tid] - tsum;
    int pj[4] = { excl, excl + c0, excl + c0 + c1, excl + c0 + c1 + c2 };
    int cj[4] = { c0, c1, c2, c3 };
    #pragma unroll
    for (int j = 0; j < 4; ++j) {
        int node = tid * 4 + j;
        if (node < nloc) {
            off[nodeBase + node]  = ebeg + pj[j];
            ndst[nodeBase + node] = rsqrtf((float)max(cj[j], 1));
        }
        cnt[node] = pj[j];   // becomes LDS cursor
    }
    __syncthreads();
    for (int e = sbeg + tid; e < send; e += 256) {
        unsigned u = dstStage[e];
        int lp = atomicAdd(&cnt[u >> 22], 1);
        esrc[ebeg + lp] = (int)(u & 0x3FFFFFu);
    }
}

// ---------------- k4: per-src-bucket: dout hist -> nsrc ----------------
__global__ __launch_bounds__(256) void dout_norm_kernel(
    const unsigned short* __restrict__ srcStage, const int* __restrict__ curS, int capS,
    float* __restrict__ nsrc, int n)
{
    __shared__ int cnt[BSZ];
    int b = blockIdx.x, tid = threadIdx.x;
    int nodeBase = b << BSHIFT;
    int nloc = min(BSZ, n - nodeBase);
    for (int i = tid; i < BSZ; i += 256) cnt[i] = 0;
    __syncthreads();
    int sbeg = b * capS, send = curS[b];
    for (int e = sbeg + tid; e < send; e += 256)
        atomicAdd(&cnt[srcStage[e]], 1);
    __syncthreads();
    for (int i = tid; i < nloc; i += 256)
        nsrc[nodeBase + i] = rsqrtf((float)max(cnt[i], 1));
}

// ---------------- MFMA GEMM: T(fp16) = (nsrc*X) @ W ----------------
// 64-row tile per block (4 waves, one 16-row tile each), N=64 = 4 col-tiles,
// K-loop in steps of 32 via v_mfma_f32_16x16x32_f16. nsrc folded into A staging.
// A and B fragments loaded with the same k-mapping -> any within-lane k
// permutation cancels between A and B; C/D layout: col=lane&15, row=(lane>>4)*4+reg.
template<int K>
__global__ __launch_bounds__(256) void gemm_mfma_kernel(
    const float* __restrict__ X, const float* __restrict__ nsrc,
    const float* __restrict__ W, __half* __restrict__ T, int n)
{
    constexpr int KP = K + 8;                 // padded halfs per row (16B-mult, bank-spread)
    __shared__ _Float16 sA[64 * KP];
    __shared__ _Float16 sW[64 * KP];          // W^T: [col][k]
    int tid = threadIdx.x;
    int brow = blockIdx.x * 64;

    // stage W^T (cvt fp32->fp16): thread t -> col c = t&63, k = (t>>6)*2 + j*8
    {
        int c = tid & 63;
        int kb = (tid >> 6) * 2;
        #pragma unroll
        for (int j = 0; j < K / 8; ++j) {
            int k = kb + j * 8;
            float w0 = W[k * 64 + c], w1 = W[(k + 1) * 64 + c];
            __half2 p = __floats2half2_rn(w0, w1);
            *(unsigned*)&sW[c * KP + k] = *(unsigned*)&p;
        }
    }
    // stage A rows (scaled by nsrc, cvt fp16)
    for (int i = tid; i < 64 * (K / 4); i += 256) {
        int rr = i / (K / 4);
        int kk = (i % (K / 4)) * 4;
        int row = brow + rr;
        float4 v = make_float4(0.f, 0.f, 0.f, 0.f);
        if (row < n) {
            v = ((const float4*)(X + (size_t)row * K))[kk >> 2];
            float s = nsrc[row];
            v.x *= s; v.y *= s; v.z *= s; v.w *= s;
        }
        __half2 p0 = __floats2half2_rn(v.x, v.y);
        __half2 p1 = __floats2half2_rn(v.z, v.w);
        uint2 u; u.x = *(unsigned*)&p0; u.y = *(unsigned*)&p1;
        *(uint2*)&sA[rr * KP + kk] = u;
    }
    __syncthreads();

    int l = tid & 63, wv = tid >> 6;
    int r = l & 15, g = l >> 4;
    const _Float16* aBase = sA + (wv * 16 + r) * KP + g * 8;
    const _Float16* bBase = sW + r * KP + g * 8;
    f32x4 acc0 = {0,0,0,0}, acc1 = {0,0,0,0}, acc2 = {0,0,0,0}, acc3 = {0,0,0,0};
    #pragma unroll
    for (int ks = 0; ks < K / 32; ++ks) {
        f16x8 a = *(const f16x8*)(aBase + ks * 32);
        f16x8 b0 = *(const f16x8*)(bBase + 0 * 16 * KP + ks * 32);
        f16x8 b1 = *(const f16x8*)(bBase + 1 * 16 * KP + ks * 32);
        f16x8 b2 = *(const f16x8*)(bBase + 2 * 16 * KP + ks * 32);
        f16x8 b3 = *(const f16x8*)(bBase + 3 * 16 * KP + ks * 32);
        acc0 = __builtin_amdgcn_mfma_f32_16x16x32_f16(a, b0, acc0, 0, 0, 0);
        acc1 = __builtin_amdgcn_mfma_f32_16x16x32_f16(a, b1, acc1, 0, 0, 0);
        acc2 = __builtin_amdgcn_mfma_f32_16x16x32_f16(a, b2, acc2, 0, 0, 0);
        acc3 = __builtin_amdgcn_mfma_f32_16x16x32_f16(a, b3, acc3, 0, 0, 0);
    }
    #pragma unroll
    for (int reg = 0; reg < 4; ++reg) {
        int row = brow + wv * 16 + g * 4 + reg;
        if (row < n) {
            __half* tp = T + (size_t)row * 64 + r;
            tp[0]  = __float2half(acc0[reg]);
            tp[16] = __float2half(acc1[reg]);
            tp[32] = __float2half(acc2[reg]);
            tp[48] = __float2half(acc3[reg]);
        }
    }
}

// ---------------- aggregation: out = agg(Tfp16) * ndst + b (opt relu) ----------------
// one wave per NPW consecutive nodes; 16 edges per main-loop pass:
// lane = (edge-group g = lane>>3, feat-chunk f = lane&7); 2 independent uint4
// gathers per lane in flight; first-level combine in fp16 (__hadd2), fp32 acc.
template<bool RELU>
__global__ __launch_bounds__(256) void aggregate_kernel(
    const uint4* __restrict__ T4, const int* __restrict__ off,
    const int* __restrict__ esrc, const float* __restrict__ ndst,
    const float* __restrict__ bias, float* __restrict__ out, int n)
{
    int wave = (blockIdx.x * 256 + threadIdx.x) >> 6;
    int lane = threadIdx.x & 63;
    int g = lane >> 3, f = lane & 7;
    float4 bb0 = ((const float4*)bias)[f * 2];
    float4 bb1 = ((const float4*)bias)[f * 2 + 1];
    int node0 = wave * NPW;
    int nodeEnd = min(node0 + NPW, n);
    for (int node = node0; node < nodeEnd; ++node) {
        int beg = off[node], end = off[node + 1];
        float a0=0,a1=0,a2=0,a3=0,a4=0,a5=0,a6=0,a7=0;
        int e = beg;
        for (; e + 16 <= end; e += 16) {
            int sa = esrc[e + g], sb = esrc[e + 8 + g];
            uint4 va = T4[(size_t)sa * 8 + f];
            uint4 vb = T4[(size_t)sb * 8 + f];
            __half2 h0 = __hadd2(*(const __half2*)&va.x, *(const __half2*)&vb.x);
            __half2 h1 = __hadd2(*(const __half2*)&va.y, *(const __half2*)&vb.y);
            __half2 h2 = __hadd2(*(const __half2*)&va.z, *(const __half2*)&vb.z);
            __half2 h3 = __hadd2(*(const __half2*)&va.w, *(const __half2*)&vb.w);
            float2 f0 = __half22float2(h0), f1 = __half22float2(h1);
            float2 f2 = __half22float2(h2), f3 = __half22float2(h3);
            a0 += f0.x; a1 += f0.y; a2 += f1.x; a3 += f1.y;
            a4 += f2.x; a5 += f2.y; a6 += f3.x; a7 += f3.y;
        }
        for (; e + 8 <= end; e += 8) {
            int s = esrc[e + g];
            uint4 v = T4[(size_t)s * 8 + f];
            float2 f0 = __half22float2(*(const __half2*)&v.x);
            float2 f1 = __half22float2(*(const __half2*)&v.y);
            float2 f2 = __half22float2(*(const __half2*)&v.z);
            float2 f3 = __half22float2(*(const __half2*)&v.w);
            a0 += f0.x; a1 += f0.y; a2 += f1.x; a3 += f1.y;
            a4 += f2.x; a5 += f2.y; a6 += f3.x; a7 += f3.y;
        }
        if (e + g < end) {
            int s = esrc[e + g];
            uint4 v = T4[(size_t)s * 8 + f];
            float2 f0 = __half22float2(*(const __half2*)&v.x);
            float2 f1 = __half22float2(*(const __half2*)&v.y);
            float2 f2 = __half22float2(*(const __half2*)&v.z);
            float2 f3 = __half22float2(*(const __half2*)&v.w);
            a0 += f0.x; a1 += f0.y; a2 += f1.x; a3 += f1.y;
            a4 += f2.x; a5 += f2.y; a6 += f3.x; a7 += f3.y;
        }
        #pragma unroll
        for (int m = 8; m <= 32; m <<= 1) {
            a0 += __shfl_xor(a0, m, 64); a1 += __shfl_xor(a1, m, 64);
            a2 += __shfl_xor(a2, m, 64); a3 += __shfl_xor(a3, m, 64);
            a4 += __shfl_xor(a4, m, 64); a5 += __shfl_xor(a5, m, 64);
            a6 += __shfl_xor(a6, m, 64); a7 += __shfl_xor(a7, m, 64);
        }
        if (g == 0) {
            float nd = ndst[node];
            float4 o0 = make_float4(a0 * nd + bb0.x, a1 * nd + bb0.y,
                                    a2 * nd + bb0.z, a3 * nd + bb0.w);
            float4 o1 = make_float4(a4 * nd + bb1.x, a5 * nd + bb1.y,
                                    a6 * nd + bb1.z, a7 * nd + bb1.w);
            if (RELU) {
                o0.x = fmaxf(o0.x, 0.f); o0.y = fmaxf(o0.y, 0.f);
                o0.z = fmaxf(o0.z, 0.f); o0.w = fmaxf(o0.w, 0.f);
                o1.x = fmaxf(o1.x, 0.f); o1.y = fmaxf(o1.y, 0.f);
                o1.z = fmaxf(o1.z, 0.f); o1.w = fmaxf(o1.w, 0.f);
            }
            ((float4*)out)[(size_t)node * 16 + f * 2]     = o0;
            ((float4*)out)[(size_t)node * 16 + f * 2 + 1] = o1;
        }
    }
}

extern "C" void kernel_launch(void* const* d_in, const int* in_sizes, int n_in,
                              void* d_out, int out_size, void* d_ws, size_t ws_size,
                              hipStream_t stream)
{
    const float* x  = (const float*)d_in[0];
    const int*   src = (const int*)d_in[1];
    const int*   dst = (const int*)d_in[2];
    const float* W1 = (const float*)d_in[3];
    const float* b1 = (const float*)d_in[4];
    const float* W2 = (const float*)d_in[5];
    const float* b2 = (const float*)d_in[6];

    const int FIN = 128;
    const int N = in_sizes[0] / FIN;
    const int E = in_sizes[1];
    const int NB = (N + BSZ - 1) >> BSHIFT;   // 98 for N=100k (<= NBCAP)

    // fixed bucket capacity: avg + 2048 (>> 16 sigma for a random graph), 256-aligned
    int cap = ((E + NB - 1) / NB + 2048 + 255) & ~255;

    char* ws = (char*)d_ws;
    size_t o = 0;
    auto carve = [&](size_t bytes) {
        void* p = ws + o;
        o = (o + bytes + 255) & ~((size_t)255);
        return p;
    };
    int* curS   = (int*)carve(NBCAP * 4);
    int* curD   = (int*)carve(NBCAP * 4);
    int* ebase  = (int*)carve((NBCAP + 1) * 4);
    int* off    = (int*)carve((size_t)(N + 1) * 4);
    float* nsrc = (float*)carve((size_t)N * 4);
    float* ndst = (float*)carve((size_t)N * 4);
    int* esrc   = (int*)carve((size_t)E * 4);
    size_t tbytes  = (size_t)N * 64 * 2;                  // fp16 t
    size_t stbytes = (size_t)NB * cap * 6 + 256;          // dstStage(4B) + srcStage(2B)
    void* tstage = carve(tbytes > stbytes ? tbytes : stbytes);
    // stage buffers alias t: both fully consumed (k3/k4) before gemm1 writes t
    __half* t = (__half*)tstage;
    unsigned* dstStage = (unsigned*)tstage;
    unsigned short* srcStage = (unsigned short*)((char*)tstage + (size_t)NB * cap * 4);

    float* h2 = (float*)d_out;
    float* h1 = (float*)d_out + (size_t)N * 64;

    int gb_e4k = (E + 4095) / 4096;
    int nwaves = (N + NPW - 1) / NPW;
    int gb_agg = (nwaves + 3) / 4;

    init_cursors_kernel<<<(NB + 255) / 256, 256, 0, stream>>>(curS, curD, NB, cap, cap);
    partition_kernel<<<gb_e4k, 256, 0, stream>>>(src, dst, curS, curD,
                                                 srcStage, dstStage, E);
    bucket_scan_kernel<<<1, 256, 0, stream>>>(curD, ebase, off, NB, cap, N, E);
    csr_build_kernel<<<NB, 256, 0, stream>>>(dstStage, curD, ebase, cap,
                                             off, ndst, esrc, N);
    dout_norm_kernel<<<NB, 256, 0, stream>>>(srcStage, curS, cap, nsrc, N);

    // layer 1: t = nsrc*(x@W1); h1 = relu(agg(t)*ndst + b1)
    gemm_mfma_kernel<128><<<(N + 63) / 64, 256, 0, stream>>>(x, nsrc, W1, t, N);
    aggregate_kernel<true><<<gb_agg, 256, 0, stream>>>((const uint4*)t, off, esrc, ndst, b1, h1, N);
    // layer 2: t = nsrc*(h1@W2); h2 = agg(t)*ndst + b2
    gemm_mfma_kernel<64><<<(N + 63) / 64, 256, 0, stream>>>(h1, nsrc, W2, t, N);
    aggregate_kernel<false><<<gb_agg, 256, 0, stream>>>((const uint4*)t, off, esrc, ndst, b2, h2, N);
}